// Round 7
// baseline (99.071 us; speedup 1.0000x reference)
//
#include <hip/hip_runtime.h>
#include <hip/hip_bf16.h>

// SpectralConv1d: out = irfft( pad( einsum('bjix,iox->bjox', rfft(x)[..:64], wr+i*wi) ), n=2048 )
// GEMM1 (DFT, KS=2/BM=64, all-DMA dbuf staging [r4 schedule], swapped-operand MFMA)
// -> stage2 (reduce 2 bf16 partials + complex mix, fp32, 512 blocks)
// -> GEMM2 (inverse DFT, swapped-operand MFMA, nontemporal dwordx4 stores, XCD swizzle).

typedef __bf16 bf16x8 __attribute__((ext_vector_type(8)));
typedef float  f32x4  __attribute__((ext_vector_type(4)));

#define SEQ 2048
#define NM2 128   // 2*MODES (Re | Im planes)
#define KS  2     // K-split for GEMM1

__device__ __forceinline__ unsigned int rnbf(float f) {
  unsigned int u = __builtin_bit_cast(unsigned int, f);
  return (u + 0x7fffu + ((u >> 16) & 1u)) >> 16;  // round-to-nearest-even bf16
}
__device__ __forceinline__ unsigned int pack2(float a, float b) {
  return rnbf(a) | (rnbf(b) << 16);
}
__device__ __forceinline__ float frombf(unsigned int lo16_in_place) {
  return __builtin_bit_cast(float, lo16_in_place);
}

typedef const __attribute__((address_space(1))) unsigned int gu32;
typedef __attribute__((address_space(3))) unsigned int lu32;

// ---------------- K0: trig tables (hw v_sin/v_cos, revolution args) ----------------
// t1sw: 32 tiles of 16 KB; tile kt = PRE-SWIZZLED LDS image of T1T[c][kt*64..+63]:
//       byte ((c*128 + part*16) ^ ((c&7)<<4)) + 2*e ; c<64: cos(2pi k n/N); c>=64: -sin
// t2t[n][c], c<64: ck*cos; c>=64: -ck*sin  (ck=1/N or 2/N)  [2048][128] bf16 linear
__global__ __launch_bounds__(256) void k_tables(unsigned short* __restrict__ t1sw,
                                                unsigned short* __restrict__ t2t) {
  int idx = blockIdx.x * 256 + threadIdx.x;   // 0..131071
  int k = idx >> 11;                          // 0..63
  int n = idx & 2047;
  float rev = (float)((k * n) & 2047) * (1.0f / 2048.0f);   // phase in revolutions
  float s, co;
  asm("v_sin_f32 %0, %1" : "=v"(s)  : "v"(rev));
  asm("v_cos_f32 %0, %1" : "=v"(co) : "v"(rev));
  float ck = (k == 0 ? 1.0f : 2.0f) * (1.0f / 2048.0f);
  int kt = n >> 6, part = (n >> 3) & 7, e = n & 7;
  unsigned base = (unsigned)kt * 16384u + 2u * (unsigned)e;
  unsigned offc = base + (((unsigned)(k * 128 + part * 16)) ^ (((unsigned)k & 7u) << 4));
  int c2 = k + 64;
  unsigned offs = base + (((unsigned)(c2 * 128 + part * 16)) ^ (((unsigned)c2 & 7u) << 4));
  *(unsigned short*)((char*)t1sw + offc) = (unsigned short)rnbf(co);
  *(unsigned short*)((char*)t1sw + offs) = (unsigned short)rnbf(-s);
  t2t[n * NM2 + k]      = (unsigned short)rnbf(ck * co);
  t2t[n * NM2 + k + 64] = (unsigned short)rnbf(-ck * s);
}

// ---------------- K1: GEMM1  P[ks][16384][128] = x[.,Kslice] @ T1[Kslice,.]  (bf16) ----
// r4-verified schedule: BM=64, BK=64, K-slice=1024 (16 iters), 64 KB LDS double-buffer,
// all staging via global_load_lds (x fp32 source-preswizzled; t1 pre-swizzled image).
// Per iter: issue STAGE(it+1) -> compute(it) -> vmcnt(0) -> barrier  (loads fly across
// the whole compute phase). fp32->bf16 at fragment read (cvt_pk). Swapped-operand MFMA
// (mfma(bv,av) = D^T): lane holds 4 consecutive cols -> 8B packed bf16 stores.
__global__ __launch_bounds__(256) void k_gemm1(const float* __restrict__ x,
                                               const unsigned short* __restrict__ t1sw,
                                               unsigned short* __restrict__ P) {
  __shared__ int4 lds4[65536 / 16];  // [0,32K): xbuf0/1 fp32 ; [32K,64K): t1buf0/1 bf16
  char* lds = (char*)lds4;
  const int tid = threadIdx.x, wave = tid >> 6, lane = tid & 63;
  const int mtile = blockIdx.x >> 1, ks = blockIdx.x & (KS - 1);
  const int r0 = mtile * 64;
  const int kbase = ks * (SEQ / KS);
  const char* t1base = (const char*)t1sw + (size_t)(kbase >> 6) * 16384;

  // x DMA sites p=0..3: stages row p*16 + wave*4 + (lane>>4); 16B unit (lane&15)^(row&7)
  const float* xsrc[4];
#pragma unroll
  for (int p = 0; p < 4; ++p) {
    const int row = p * 16 + wave * 4 + (lane >> 4);
    const int u = (lane & 15) ^ (row & 7);
    xsrc[p] = x + (size_t)(r0 + row) * SEQ + kbase + u * 4;
  }

  f32x4 acc[8] = {};

  // ---- prologue: stage tile 0 ----
#pragma unroll
  for (int p = 0; p < 4; ++p)
    __builtin_amdgcn_global_load_lds((gu32*)(xsrc[p]),
                                     (lu32*)(lds + p * 4096 + wave * 1024), 16, 0, 0);
#pragma unroll
  for (int p = 0; p < 4; ++p)
    __builtin_amdgcn_global_load_lds((gu32*)(t1base + (p * 256 + tid) * 16),
                                     (lu32*)(lds + 32768 + (p * 256 + wave * 64) * 16), 16, 0, 0);
  asm volatile("s_waitcnt vmcnt(0)" ::: "memory");
  __builtin_amdgcn_s_barrier();

  const int a = wave * 16 + (lane & 15);
  const unsigned xra = (unsigned)(a & 7) << 4;
  const int kg = lane >> 4;

  for (int it = 0; it < 16; ++it) {
    const int cur = it & 1, nxt = cur ^ 1;
    const int xoff = cur * 16384;
    const int toff = 32768 + cur * 16384;
    // ---- issue STAGE(it+1): 8 DMA ops fly across the whole compute phase ----
    if (it < 15) {
      const char* tg = t1base + (size_t)(it + 1) * 16384;
#pragma unroll
      for (int p = 0; p < 4; ++p)
        __builtin_amdgcn_global_load_lds((gu32*)(xsrc[p] + (it + 1) * 64),
                                         (lu32*)(lds + nxt * 16384 + p * 4096 + wave * 1024),
                                         16, 0, 0);
#pragma unroll
      for (int p = 0; p < 4; ++p)
        __builtin_amdgcn_global_load_lds((gu32*)(tg + (p * 256 + tid) * 16),
                                         (lu32*)(lds + 32768 + nxt * 16384 + (p * 256 + wave * 64) * 16),
                                         16, 0, 0);
    }
    // ---- compute tile it ----
#pragma unroll
    for (int kss = 0; kss < 2; ++kss) {
      const unsigned byte0 = (unsigned)(a * 256 + kss * 128 + kg * 32);
      const f32x4 lo = *(const f32x4*)(lds + xoff + (byte0 ^ xra));
      const f32x4 hi = *(const f32x4*)(lds + xoff + ((byte0 + 16) ^ xra));
      unsigned c0, c1, c2, c3;
      asm("v_cvt_pk_bf16_f32 %0, %1, %2" : "=v"(c0) : "v"(lo[0]), "v"(lo[1]));
      asm("v_cvt_pk_bf16_f32 %0, %1, %2" : "=v"(c1) : "v"(lo[2]), "v"(lo[3]));
      asm("v_cvt_pk_bf16_f32 %0, %1, %2" : "=v"(c2) : "v"(hi[0]), "v"(hi[1]));
      asm("v_cvt_pk_bf16_f32 %0, %1, %2" : "=v"(c3) : "v"(hi[2]), "v"(hi[3]));
      uint4 pk; pk.x = c0; pk.y = c1; pk.z = c2; pk.w = c3;
      const bf16x8 av = __builtin_bit_cast(bf16x8, pk);
#pragma unroll
      for (int t = 0; t < 8; ++t) {
        const int col = t * 16 + (lane & 15);
        const bf16x8 bv = *(const bf16x8*)(lds + toff +
            ((col * 128 + kss * 64 + kg * 16) ^ ((unsigned)(col & 7) << 4)));
        acc[t] = __builtin_amdgcn_mfma_f32_16x16x32_bf16(bv, av, acc[t], 0, 0, 0);  // D^T
      }
    }
    // ---- single drain per iter; stages had the whole compute phase to land ----
    asm volatile("s_waitcnt vmcnt(0)" ::: "memory");
    __builtin_amdgcn_s_barrier();
  }
  // epilogue (swapped layout): lane holds row = wave*16+(lane&15), cols kg*4+{0..3}
  unsigned short* Pout = P + (size_t)ks * (16384 * NM2);
  const int row = r0 + wave * 16 + (lane & 15);
#pragma unroll
  for (int t = 0; t < 8; ++t) {
    const int col0 = t * 16 + kg * 4;
    uint2 v; v.x = pack2(acc[t][0], acc[t][1]); v.y = pack2(acc[t][2], acc[t][3]);
    *(uint2*)(Pout + (size_t)row * NM2 + col0) = v;
  }
}

// ---------------- K2: reduce bf16 partials + complex channel mix (fp32 VALU) ---------
// A = P[0]+P[1]; B[bj,o,k] = sum_i (Ar+iAi)[bj,i,k]*(wr+iwi)[i,o,k]; Bx[r][k|64+k] bf16
// 512 blocks: (bjc: 2 bj-groups) x (o half) x (k half); sA 32 KB -> high occupancy.
__global__ __launch_bounds__(256) void k_stage2(const unsigned short* __restrict__ P,
                                                const float* __restrict__ wr,
                                                const float* __restrict__ wi,
                                                unsigned short* __restrict__ Bx) {
  __shared__ float sA[2][64][64];   // [bj][i][ 0..31: Ar(k0+c) | 32..63: Ai(k0+c) ]
  const int b = blockIdx.x;
  const int bjc = b >> 2, oh = (b >> 1) & 1, kh = b & 1;
  const int k0 = kh * 32;
  const int tid = threadIdx.x;
#pragma unroll
  for (int p = 0; p < 8; ++p) {
    int fidx = tid + 256 * p;               // quad index 0..2047
    int row = fidx >> 4, q = fidx & 15;
    int colbf = (q < 8) ? (k0 + q * 4) : (64 + k0 + (q - 8) * 4);
    const unsigned short* base = P + (size_t)(bjc * 128 + row) * NM2 + colbf;
    uint2 u0 = *(const uint2*)(base);
    uint2 u1 = *(const uint2*)(base + (size_t)16384 * NM2);
    f32x4 v;
    v[0] = frombf(u0.x << 16)         + frombf(u1.x << 16);
    v[1] = frombf(u0.x & 0xffff0000u) + frombf(u1.x & 0xffff0000u);
    v[2] = frombf(u0.y << 16)         + frombf(u1.y << 16);
    v[3] = frombf(u0.y & 0xffff0000u) + frombf(u1.y & 0xffff0000u);
    int dcol = (q < 8) ? q * 4 : 32 + (q - 8) * 4;
    *(f32x4*)(&sA[row >> 6][row & 63][dcol]) = v;
  }
  __syncthreads();
  const int o = oh * 32 + (tid >> 3);
  const int kg = tid & 7;
  const int kb = k0 + kg * 4;
  f32x4 accr[2] = {};
  f32x4 acci[2] = {};
  for (int i = 0; i < 64; ++i) {
    f32x4 wrv = *(const f32x4*)(wr + (i * 64 + o) * 64 + kb);
    f32x4 wiv = *(const f32x4*)(wi + (i * 64 + o) * 64 + kb);
#pragma unroll
    for (int bj = 0; bj < 2; ++bj) {
      f32x4 ar = *(const f32x4*)(&sA[bj][i][kg * 4]);
      f32x4 ai = *(const f32x4*)(&sA[bj][i][32 + kg * 4]);
#pragma unroll
      for (int kk = 0; kk < 4; ++kk) {
        accr[bj][kk] += ar[kk] * wrv[kk] - ai[kk] * wiv[kk];
        acci[bj][kk] += ar[kk] * wiv[kk] + ai[kk] * wrv[kk];
      }
    }
  }
#pragma unroll
  for (int bj = 0; bj < 2; ++bj) {
    const int r = (bjc * 2 + bj) * 64 + o;
    uint2 vr; vr.x = pack2(accr[bj][0], accr[bj][1]); vr.y = pack2(accr[bj][2], accr[bj][3]);
    uint2 vi; vi.x = pack2(acci[bj][0], acci[bj][1]); vi.y = pack2(acci[bj][2], acci[bj][3]);
    *(uint2*)(Bx + (size_t)r * NM2 + kb)      = vr;
    *(uint2*)(Bx + (size_t)r * NM2 + 64 + kb) = vi;
  }
}

// ---------------- K3: GEMM2  out[16384][2048] = Bx[16384][128] @ T2 ----------------
// BM=128, BN=128, K=128 fully in LDS. Swapped-operand MFMA -> each lane holds 4
// consecutive out cols -> NONTEMPORAL global_store_dwordx4. XCD-aware block swizzle.
__global__ __launch_bounds__(256) void k_gemm2(const unsigned short* __restrict__ Bx,
                                               const unsigned short* __restrict__ t2t,
                                               float* __restrict__ out) {
  __shared__ int4 lds4[65536 / 16];
  char* lds = (char*)lds4;
  const int tid = threadIdx.x, wave = tid >> 6, lane = tid & 63;
  const int swz = (blockIdx.x & 7) * 256 + (blockIdx.x >> 3);   // XCD-contiguous
  const int mb = swz >> 4, nb = swz & 15;
  const int r0 = mb * 128, n0 = nb * 128;
#pragma unroll
  for (int p = 0; p < 8; ++p) {
    int seg = tid + 256 * p;        // 0..2047
    int row = seg >> 4, part = seg & 15;
    unsigned sw = (unsigned)((row * 256 + part * 16) ^ ((row & 7) << 4));
    int4 va = *(const int4*)(Bx + (size_t)(r0 + row) * NM2 + part * 8);
    *(int4*)(lds + sw) = va;
    int4 vb = *(const int4*)(t2t + (size_t)(n0 + row) * NM2 + part * 8);
    *(int4*)(lds + 32768 + sw) = vb;
  }
  __syncthreads();
  f32x4 acc[2][8] = {};
#pragma unroll
  for (int ks = 0; ks < 4; ++ks) {
    const int ar0 = wave * 32 + (lane & 15);
    const int ar1 = ar0 + 16;
    const int koff = ks * 64 + (lane >> 4) * 16;
    bf16x8 a0 = *(const bf16x8*)(lds + ((ar0 * 256 + koff) ^ ((unsigned)(ar0 & 7) << 4)));
    bf16x8 a1 = *(const bf16x8*)(lds + ((ar1 * 256 + koff) ^ ((unsigned)(ar1 & 7) << 4)));
#pragma unroll
    for (int t = 0; t < 8; ++t) {
      const int col = t * 16 + (lane & 15);
      bf16x8 bv = *(const bf16x8*)(lds + 32768 + ((col * 256 + koff) ^ ((unsigned)(col & 7) << 4)));
      acc[0][t] = __builtin_amdgcn_mfma_f32_16x16x32_bf16(bv, a0, acc[0][t], 0, 0, 0);  // D^T
      acc[1][t] = __builtin_amdgcn_mfma_f32_16x16x32_bf16(bv, a1, acc[1][t], 0, 0, 0);
    }
  }
  // store: lane row = lane&15, 4 consecutive cols = (lane>>4)*4 -> nontemporal dwordx4
#pragma unroll
  for (int m = 0; m < 2; ++m) {
    const int row = r0 + wave * 32 + m * 16 + (lane & 15);
#pragma unroll
    for (int t = 0; t < 8; ++t) {
      const int col = n0 + t * 16 + (lane >> 4) * 4;
      __builtin_nontemporal_store(acc[m][t], (f32x4*)(out + (size_t)row * SEQ + col));
    }
  }
}

extern "C" void kernel_launch(void* const* d_in, const int* in_sizes, int n_in,
                              void* d_out, int out_size, void* d_ws, size_t ws_size,
                              hipStream_t stream) {
  const float* x  = (const float*)d_in[0];
  const float* wr = (const float*)d_in[1];
  const float* wi = (const float*)d_in[2];
  float* out = (float*)d_out;
  char* ws = (char*)d_ws;
  // ws layout: t1sw 512K | t2t 512K | P (bf16) 2x4M = 8M | Bx 4M   (total ~13 MB)
  unsigned short* t1sw = (unsigned short*)(ws);
  unsigned short* t2t  = (unsigned short*)(ws + 524288);
  unsigned short* P    = (unsigned short*)(ws + 1048576);
  unsigned short* Bx   = (unsigned short*)(ws + 1048576 + (size_t)KS * 16384 * NM2 * 2);

  k_tables<<<dim3(512),      dim3(256), 0, stream>>>(t1sw, t2t);
  k_gemm1 <<<dim3(256 * KS), dim3(256), 0, stream>>>(x, t1sw, P);
  k_stage2<<<dim3(512),      dim3(256), 0, stream>>>(P, wr, wi, Bx);
  k_gemm2 <<<dim3(2048),     dim3(256), 0, stream>>>(Bx, t2t, out);
}

// Round 8
// 89.479 us; speedup vs baseline: 1.1072x; 1.1072x over previous
//
#include <hip/hip_runtime.h>
#include <hip/hip_bf16.h>

// SpectralConv1d: out = irfft( pad( einsum('bjix,iox->bjox', rfft(x)[..:64], wr+i*wi) ), n=2048 )
// GEMM1 (DFT, KS=2/BM=64, all-DMA dbuf staging, swapped-operand MFMA epilogue)
// -> stage2 (r4: 256 blocks, 4 bj, reduce bf16 partials + complex mix, fp32)
// -> GEMM2 (r4: inverse DFT, normal-order MFMA, t-inner scalar stores, XCD swizzle).

typedef __bf16 bf16x8 __attribute__((ext_vector_type(8)));
typedef float  f32x4  __attribute__((ext_vector_type(4)));

#define SEQ 2048
#define NM2 128   // 2*MODES (Re | Im planes)
#define KS  2     // K-split for GEMM1

__device__ __forceinline__ unsigned int rnbf(float f) {
  unsigned int u = __builtin_bit_cast(unsigned int, f);
  return (u + 0x7fffu + ((u >> 16) & 1u)) >> 16;  // round-to-nearest-even bf16
}
__device__ __forceinline__ unsigned int pack2(float a, float b) {
  return rnbf(a) | (rnbf(b) << 16);
}
__device__ __forceinline__ float frombf(unsigned int lo16_in_place) {
  return __builtin_bit_cast(float, lo16_in_place);
}

typedef const __attribute__((address_space(1))) unsigned int gu32;
typedef __attribute__((address_space(3))) unsigned int lu32;

// ---------------- K0: trig tables (hw v_sin/v_cos, revolution args) ----------------
// t1sw: 32 tiles of 16 KB; tile kt = PRE-SWIZZLED LDS image of T1T[c][kt*64..+63]:
//       byte ((c*128 + part*16) ^ ((c&7)<<4)) + 2*e ; c<64: cos(2pi k n/N); c>=64: -sin
// t2t[n][c], c<64: ck*cos; c>=64: -ck*sin  (ck=1/N or 2/N)  [2048][128] bf16 linear
__global__ __launch_bounds__(256) void k_tables(unsigned short* __restrict__ t1sw,
                                                unsigned short* __restrict__ t2t) {
  int idx = blockIdx.x * 256 + threadIdx.x;   // 0..131071
  int k = idx >> 11;                          // 0..63
  int n = idx & 2047;
  float rev = (float)((k * n) & 2047) * (1.0f / 2048.0f);   // phase in revolutions
  float s, co;
  asm("v_sin_f32 %0, %1" : "=v"(s)  : "v"(rev));
  asm("v_cos_f32 %0, %1" : "=v"(co) : "v"(rev));
  float ck = (k == 0 ? 1.0f : 2.0f) * (1.0f / 2048.0f);
  int kt = n >> 6, part = (n >> 3) & 7, e = n & 7;
  unsigned base = (unsigned)kt * 16384u + 2u * (unsigned)e;
  unsigned offc = base + (((unsigned)(k * 128 + part * 16)) ^ (((unsigned)k & 7u) << 4));
  int c2 = k + 64;
  unsigned offs = base + (((unsigned)(c2 * 128 + part * 16)) ^ (((unsigned)c2 & 7u) << 4));
  *(unsigned short*)((char*)t1sw + offc) = (unsigned short)rnbf(co);
  *(unsigned short*)((char*)t1sw + offs) = (unsigned short)rnbf(-s);
  t2t[n * NM2 + k]      = (unsigned short)rnbf(ck * co);
  t2t[n * NM2 + k + 64] = (unsigned short)rnbf(-ck * s);
}

// ---------------- K1: GEMM1  P[ks][16384][128] = x[.,Kslice] @ T1[Kslice,.]  (bf16) ----
// r4 schedule: BM=64, BK=64, K-slice=1024 (16 iters), 64 KB LDS double-buffer, all
// staging via global_load_lds. Per iter: issue STAGE(it+1) -> compute(it) -> vmcnt(0)
// -> barrier. fp32->bf16 at fragment read. Swapped-operand MFMA (D^T) -> packed stores.
__global__ __launch_bounds__(256) void k_gemm1(const float* __restrict__ x,
                                               const unsigned short* __restrict__ t1sw,
                                               unsigned short* __restrict__ P) {
  __shared__ int4 lds4[65536 / 16];  // [0,32K): xbuf0/1 fp32 ; [32K,64K): t1buf0/1 bf16
  char* lds = (char*)lds4;
  const int tid = threadIdx.x, wave = tid >> 6, lane = tid & 63;
  const int mtile = blockIdx.x >> 1, ks = blockIdx.x & (KS - 1);
  const int r0 = mtile * 64;
  const int kbase = ks * (SEQ / KS);
  const char* t1base = (const char*)t1sw + (size_t)(kbase >> 6) * 16384;

  // x DMA sites p=0..3: stages row p*16 + wave*4 + (lane>>4); 16B unit (lane&15)^(row&7)
  const float* xsrc[4];
#pragma unroll
  for (int p = 0; p < 4; ++p) {
    const int row = p * 16 + wave * 4 + (lane >> 4);
    const int u = (lane & 15) ^ (row & 7);
    xsrc[p] = x + (size_t)(r0 + row) * SEQ + kbase + u * 4;
  }

  f32x4 acc[8] = {};

  // ---- prologue: stage tile 0 ----
#pragma unroll
  for (int p = 0; p < 4; ++p)
    __builtin_amdgcn_global_load_lds((gu32*)(xsrc[p]),
                                     (lu32*)(lds + p * 4096 + wave * 1024), 16, 0, 0);
#pragma unroll
  for (int p = 0; p < 4; ++p)
    __builtin_amdgcn_global_load_lds((gu32*)(t1base + (p * 256 + tid) * 16),
                                     (lu32*)(lds + 32768 + (p * 256 + wave * 64) * 16), 16, 0, 0);
  asm volatile("s_waitcnt vmcnt(0)" ::: "memory");
  __builtin_amdgcn_s_barrier();

  const int a = wave * 16 + (lane & 15);
  const unsigned xra = (unsigned)(a & 7) << 4;
  const int kg = lane >> 4;

  for (int it = 0; it < 16; ++it) {
    const int cur = it & 1, nxt = cur ^ 1;
    const int xoff = cur * 16384;
    const int toff = 32768 + cur * 16384;
    // ---- issue STAGE(it+1): 8 DMA ops fly across the whole compute phase ----
    if (it < 15) {
      const char* tg = t1base + (size_t)(it + 1) * 16384;
#pragma unroll
      for (int p = 0; p < 4; ++p)
        __builtin_amdgcn_global_load_lds((gu32*)(xsrc[p] + (it + 1) * 64),
                                         (lu32*)(lds + nxt * 16384 + p * 4096 + wave * 1024),
                                         16, 0, 0);
#pragma unroll
      for (int p = 0; p < 4; ++p)
        __builtin_amdgcn_global_load_lds((gu32*)(tg + (p * 256 + tid) * 16),
                                         (lu32*)(lds + 32768 + nxt * 16384 + (p * 256 + wave * 64) * 16),
                                         16, 0, 0);
    }
    // ---- compute tile it ----
#pragma unroll
    for (int kss = 0; kss < 2; ++kss) {
      const unsigned byte0 = (unsigned)(a * 256 + kss * 128 + kg * 32);
      const f32x4 lo = *(const f32x4*)(lds + xoff + (byte0 ^ xra));
      const f32x4 hi = *(const f32x4*)(lds + xoff + ((byte0 + 16) ^ xra));
      unsigned c0, c1, c2, c3;
      asm("v_cvt_pk_bf16_f32 %0, %1, %2" : "=v"(c0) : "v"(lo[0]), "v"(lo[1]));
      asm("v_cvt_pk_bf16_f32 %0, %1, %2" : "=v"(c1) : "v"(lo[2]), "v"(lo[3]));
      asm("v_cvt_pk_bf16_f32 %0, %1, %2" : "=v"(c2) : "v"(hi[0]), "v"(hi[1]));
      asm("v_cvt_pk_bf16_f32 %0, %1, %2" : "=v"(c3) : "v"(hi[2]), "v"(hi[3]));
      uint4 pk; pk.x = c0; pk.y = c1; pk.z = c2; pk.w = c3;
      const bf16x8 av = __builtin_bit_cast(bf16x8, pk);
#pragma unroll
      for (int t = 0; t < 8; ++t) {
        const int col = t * 16 + (lane & 15);
        const bf16x8 bv = *(const bf16x8*)(lds + toff +
            ((col * 128 + kss * 64 + kg * 16) ^ ((unsigned)(col & 7) << 4)));
        acc[t] = __builtin_amdgcn_mfma_f32_16x16x32_bf16(bv, av, acc[t], 0, 0, 0);  // D^T
      }
    }
    // ---- single drain per iter; stages had the whole compute phase to land ----
    asm volatile("s_waitcnt vmcnt(0)" ::: "memory");
    __builtin_amdgcn_s_barrier();
  }
  // epilogue (swapped layout): lane holds row = wave*16+(lane&15), cols kg*4+{0..3}
  unsigned short* Pout = P + (size_t)ks * (16384 * NM2);
  const int row = r0 + wave * 16 + (lane & 15);
#pragma unroll
  for (int t = 0; t < 8; ++t) {
    const int col0 = t * 16 + kg * 4;
    uint2 v; v.x = pack2(acc[t][0], acc[t][1]); v.y = pack2(acc[t][2], acc[t][3]);
    *(uint2*)(Pout + (size_t)row * NM2 + col0) = v;
  }
}

// ---------------- K2 (r4): reduce bf16 partials + complex channel mix (fp32 VALU) ----
// A = sum_ks P[ks]; B[bj,o,k] = sum_i (Ar+iAi)[bj,i,k]*(wr+iwi)[i,o,k]; Bx[r][k|64+k]
// 256 blocks: (bjc: 4 bj-groups) x (o half) x (k half); sA 64 KB.
__global__ __launch_bounds__(256) void k_stage2(const unsigned short* __restrict__ P,
                                                const float* __restrict__ wr,
                                                const float* __restrict__ wi,
                                                unsigned short* __restrict__ Bx) {
  __shared__ float sA[4][64][64];   // [bj][i][ 0..31: Ar(k0+c) | 32..63: Ai(k0+c) ]
  const int b = blockIdx.x;
  const int bjc = b >> 2, oh = (b >> 1) & 1, kh = b & 1;
  const int k0 = kh * 32;
  const int tid = threadIdx.x;
#pragma unroll
  for (int p = 0; p < 16; ++p) {
    int fidx = tid + 256 * p;               // quad index 0..4095
    int row_lin = fidx >> 4, q = fidx & 15;
    int col = (q < 8) ? (k0 + q * 4) : (64 + k0 + (q - 8) * 4);
    const unsigned short* base = P + (size_t)(bjc * 256 + row_lin) * NM2 + col;
    f32x4 v = {};
#pragma unroll
    for (int s = 0; s < KS; ++s) {
      uint2 u = *(const uint2*)(base + (size_t)s * (16384 * NM2));
      v[0] += frombf(u.x << 16);
      v[1] += frombf(u.x & 0xffff0000u);
      v[2] += frombf(u.y << 16);
      v[3] += frombf(u.y & 0xffff0000u);
    }
    *(f32x4*)(&sA[row_lin >> 6][row_lin & 63][q * 4]) = v;
  }
  __syncthreads();
  const int o_l = tid >> 3, kg = tid & 7;
  const int o = oh * 32 + o_l;
  const int kb = k0 + kg * 4;
  f32x4 accr[4] = {};
  f32x4 acci[4] = {};
  for (int i = 0; i < 64; ++i) {
    f32x4 wrv = *(const f32x4*)(wr + (i * 64 + o) * 64 + kb);
    f32x4 wiv = *(const f32x4*)(wi + (i * 64 + o) * 64 + kb);
#pragma unroll
    for (int bj = 0; bj < 4; ++bj) {
      f32x4 ar = *(const f32x4*)(&sA[bj][i][kg * 4]);
      f32x4 ai = *(const f32x4*)(&sA[bj][i][32 + kg * 4]);
#pragma unroll
      for (int kk = 0; kk < 4; ++kk) {
        accr[bj][kk] += ar[kk] * wrv[kk] - ai[kk] * wiv[kk];
        acci[bj][kk] += ar[kk] * wiv[kk] + ai[kk] * wrv[kk];
      }
    }
  }
#pragma unroll
  for (int bj = 0; bj < 4; ++bj) {
    const int r = (bjc * 4 + bj) * 64 + o;
    uint2 vr; vr.x = pack2(accr[bj][0], accr[bj][1]); vr.y = pack2(accr[bj][2], accr[bj][3]);
    uint2 vi; vi.x = pack2(acci[bj][0], acci[bj][1]); vi.y = pack2(acci[bj][2], acci[bj][3]);
    *(uint2*)(Bx + (size_t)r * NM2 + kb)      = vr;
    *(uint2*)(Bx + (size_t)r * NM2 + 64 + kb) = vi;
  }
}

// ---------------- K3 (r4): GEMM2  out[16384][2048] = Bx[16384][128] @ T2 -------------
// BM=128, BN=128, K=128 fully in LDS. Normal-order MFMA; store t-innermost
// (per row 8 back-to-back 64B bursts). XCD-aware block swizzle.
__global__ __launch_bounds__(256) void k_gemm2(const unsigned short* __restrict__ Bx,
                                               const unsigned short* __restrict__ t2t,
                                               float* __restrict__ out) {
  __shared__ int4 lds4[65536 / 16];
  char* lds = (char*)lds4;
  const int tid = threadIdx.x, wave = tid >> 6, lane = tid & 63;
  const int swz = (blockIdx.x & 7) * 256 + (blockIdx.x >> 3);   // XCD-contiguous
  const int mb = swz >> 4, nb = swz & 15;
  const int r0 = mb * 128, n0 = nb * 128;
#pragma unroll
  for (int p = 0; p < 8; ++p) {
    int seg = tid + 256 * p;        // 0..2047
    int row = seg >> 4, part = seg & 15;
    unsigned sw = (unsigned)((row * 256 + part * 16) ^ ((row & 7) << 4));
    int4 va = *(const int4*)(Bx + (size_t)(r0 + row) * NM2 + part * 8);
    *(int4*)(lds + sw) = va;
    int4 vb = *(const int4*)(t2t + (size_t)(n0 + row) * NM2 + part * 8);
    *(int4*)(lds + 32768 + sw) = vb;
  }
  __syncthreads();
  f32x4 acc[2][8] = {};
#pragma unroll
  for (int ks = 0; ks < 4; ++ks) {
    const int ar0 = wave * 32 + (lane & 15);
    const int ar1 = ar0 + 16;
    const int koff = ks * 64 + (lane >> 4) * 16;
    bf16x8 a0 = *(const bf16x8*)(lds + ((ar0 * 256 + koff) ^ ((unsigned)(ar0 & 7) << 4)));
    bf16x8 a1 = *(const bf16x8*)(lds + ((ar1 * 256 + koff) ^ ((unsigned)(ar1 & 7) << 4)));
#pragma unroll
    for (int t = 0; t < 8; ++t) {
      const int col = t * 16 + (lane & 15);
      bf16x8 bv = *(const bf16x8*)(lds + 32768 + ((col * 256 + koff) ^ ((unsigned)(col & 7) << 4)));
      acc[0][t] = __builtin_amdgcn_mfma_f32_16x16x32_bf16(a0, bv, acc[0][t], 0, 0, 0);
      acc[1][t] = __builtin_amdgcn_mfma_f32_16x16x32_bf16(a1, bv, acc[1][t], 0, 0, 0);
    }
  }
  // store: t innermost -> per row 8 back-to-back 64B stores (full 512B span, L2 merge)
#pragma unroll
  for (int m = 0; m < 2; ++m) {
#pragma unroll
    for (int j = 0; j < 4; ++j) {
      const int row = r0 + wave * 32 + m * 16 + (lane >> 4) * 4 + j;
#pragma unroll
      for (int t = 0; t < 8; ++t) {
        const int col = n0 + t * 16 + (lane & 15);
        out[(size_t)row * SEQ + col] = acc[m][t][j];
      }
    }
  }
}

extern "C" void kernel_launch(void* const* d_in, const int* in_sizes, int n_in,
                              void* d_out, int out_size, void* d_ws, size_t ws_size,
                              hipStream_t stream) {
  const float* x  = (const float*)d_in[0];
  const float* wr = (const float*)d_in[1];
  const float* wi = (const float*)d_in[2];
  float* out = (float*)d_out;
  char* ws = (char*)d_ws;
  // ws layout: t1sw 512K | t2t 512K | P (bf16) 2x4M = 8M | Bx 4M   (total ~13 MB)
  unsigned short* t1sw = (unsigned short*)(ws);
  unsigned short* t2t  = (unsigned short*)(ws + 524288);
  unsigned short* P    = (unsigned short*)(ws + 1048576);
  unsigned short* Bx   = (unsigned short*)(ws + 1048576 + (size_t)KS * 16384 * NM2 * 2);

  k_tables<<<dim3(512),      dim3(256), 0, stream>>>(t1sw, t2t);
  k_gemm1 <<<dim3(256 * KS), dim3(256), 0, stream>>>(x, t1sw, P);
  k_stage2<<<dim3(256),      dim3(256), 0, stream>>>(P, wr, wi, Bx);
  k_gemm2 <<<dim3(2048),     dim3(256), 0, stream>>>(Bx, t2t, out);
}